// Round 11
// baseline (234.614 us; speedup 1.0000x reference)
//
#include <hip/hip_runtime.h>
#include <hip/hip_bf16.h>

typedef __hip_bfloat16 bf16;
// match the builtin's own return type (__fp16 ext_vector(2)) exactly
using hf2 = decltype(__builtin_amdgcn_cvt_pkrtz(0.f, 0.f));
typedef float f32x2 __attribute__((ext_vector_type(2)));
typedef _Float16 v4h __attribute__((ext_vector_type(4)));   // MFMA A/B frag
typedef float v4f __attribute__((ext_vector_type(4)));      // MFMA C/D frag

// ---------------------------------------------------------------------------
// Problem constants
// ---------------------------------------------------------------------------
#define BB   2
#define FF   16
#define HH   64
#define WW   64
#define CC   16     // in/out channels == MID
#define NIMG (BB*FF)        // 32
#define PIX  (HH*WW)        // 4096
#define IMGSZ (PIX*CC)      // 65536 elements per image (channel-last)

// scale(=1/sqrt(2)) * log2(e): folded into staged Wq; softmax uses raw v_exp_f32
#define QSCALE_LOG2E 1.0201394f

// ---- packed f16x2 helpers (v_cvt_pkrtz_f16_f32 / v_dot2_f32_f16) ----
__device__ __forceinline__ unsigned pkh2(float a, float b) {
    union { hf2 h; unsigned u; } x;
    x.h = __builtin_amdgcn_cvt_pkrtz(a, b);
    return x.u;
}
__device__ __forceinline__ float fdot2u(unsigned a, unsigned b, float c) {
    union { unsigned u; hf2 h; } A, B;
    A.u = a; B.u = b;
    return __builtin_amdgcn_fdot2(A.h, B.h, c, false);
}
__device__ __forceinline__ f32x2 f2(float a, float b) {
    f32x2 r; r.x = a; r.y = b; return r;
}

// ---- 16-element fp32 I/O ----
__device__ __forceinline__ void ld16f(const float* p, float* x) {
    const float4* p4 = reinterpret_cast<const float4*>(p);
    #pragma unroll
    for (int q = 0; q < 4; ++q) {
        float4 v = p4[q];
        x[4 * q] = v.x; x[4 * q + 1] = v.y; x[4 * q + 2] = v.z; x[4 * q + 3] = v.w;
    }
}

__device__ __forceinline__ unsigned packbf2(float a, float b) {
    union { bf16 h[2]; unsigned u; } pk;
    pk.h[0] = __float2bfloat16(a);
    pk.h[1] = __float2bfloat16(b);
    return pk.u;
}

// Conv weight prepack into MFMA-B layout: wB[(tap*4+chunk)*16+oc] = 4 f16 of
// w[oc][ic=chunk*4..+3][tap].  576 8-byte entries (4.6 KB).
__device__ __forceinline__ void stage_wB(const float* __restrict__ w,
                                         unsigned* __restrict__ wB, int t) {
    for (int e = t; e < 576; e += 256) {
        int oc = e & 15;
        int c  = (e >> 4) & 3;
        int s  = e >> 6;                 // tap 0..8
        const float* wp = w + (oc * 16 + c * 4) * 9 + s;   // ic stride = 9
        wB[e * 2]     = pkh2(wp[0],  wp[9]);
        wB[e * 2 + 1] = pkh2(wp[18], wp[27]);
    }
}

// per-tap LDS (uint) offset inside the halo-staged tile:
// taps s=0..8 -> (dy,dx) = (s/3-1, s%3-1); corner-biased base => offset
// ((s/3)*66 + s%3) * 12 uints (compile-time per unrolled step).
#define TAP_OFF(s) ((((s) / 3) * 66 + ((s) % 3)) * 12)

// ---------------------------------------------------------------------------
// Kernel 1 (MFMA): conv stem on hidden (->A) and ref (->R, + fused emb-MLP).
// ---------------------------------------------------------------------------
__global__ __launch_bounds__(256) void conv_in_kernel(
    const float* __restrict__ hid, const float* __restrict__ ref,
    const float* __restrict__ cw, const float* __restrict__ cb,
    const float* __restrict__ emb,
    const float* __restrict__ e1w, const float* __restrict__ e1b,
    const float* __restrict__ e2w, const float* __restrict__ e2b,
    bf16* __restrict__ A, bf16* __restrict__ R)
{
    __shared__ __align__(16) unsigned stg[6 * 66 * 12];   // 19008 B
    __shared__ __align__(16) unsigned wB[1152];           // 4608 B
    __shared__ float bl[16], hl[16], el[16];

    int t = threadIdx.x;
    int bid = blockIdx.x;          // 1024 blocks
    int rg   = bid & 15;
    int img2 = bid >> 4;           // 0..63, block-uniform
    int isref = img2 >> 5;
    int img   = img2 & 31;
    int bi    = img >> 4;
    int r0    = rg << 2;

    stage_wB(cw, wB, t);
    if (t < 16) bl[t] = cb[t];

    if (isref) {   // block-uniform branch: internal barriers safe
        float* red = reinterpret_cast<float*>(stg);   // overlay, freed below
        {
            int o = t >> 4, seg = t & 15;
            const float* er = emb + bi * 512 + seg * 32;
            const float* wr = e1w + o * 512 + seg * 32;
            float p = 0.f;
            #pragma unroll
            for (int k = 0; k < 32; ++k) p = fmaf(er[k], wr[k], p);
            red[t] = p;
        }
        __syncthreads();
        if (t < 16) {
            float acc = e1b[t];
            #pragma unroll
            for (int s = 0; s < 16; ++s) acc += red[t * 16 + s];
            hl[t] = acc / (1.f + __expf(-acc));   // silu
        }
        __syncthreads();
        if (t < 16) {
            float acc = e2b[t];
            #pragma unroll
            for (int k = 0; k < 16; ++k) acc = fmaf(hl[k], e2w[t * 16 + k], acc);
            el[t] = acc;
        }
        __syncthreads();   // red region free
    }

    // ---- stage 6 halo rows (r0-1..r0+4) x 66 cols, f16x2-packed ----
    const float* inp = (isref ? ref : hid) + (size_t)img * IMGSZ;
    for (int s2 = t; s2 < 396; s2 += 256) {
        int rr = s2 / 66, xi = s2 - rr * 66;
        int y = r0 - 1 + rr, px = xi - 1;
        uint4* dst = reinterpret_cast<uint4*>(&stg[(rr * 66 + xi) * 12]);
        if ((unsigned)y < 64u && (unsigned)px < 64u) {
            float xv[16];
            ld16f(inp + (((y << 6) + px) << 4), xv);
            dst[0] = make_uint4(pkh2(xv[0], xv[1]),  pkh2(xv[2], xv[3]),
                                pkh2(xv[4], xv[5]),  pkh2(xv[6], xv[7]));
            dst[1] = make_uint4(pkh2(xv[8], xv[9]),  pkh2(xv[10], xv[11]),
                                pkh2(xv[12], xv[13]), pkh2(xv[14], xv[15]));
        } else {
            dst[0] = make_uint4(0, 0, 0, 0);
            dst[1] = make_uint4(0, 0, 0, 0);
        }
    }
    __syncthreads();

    // ---- implicit-GEMM conv via MFMA ----
    int l  = t & 63, w = t >> 6;
    int oc = l & 15, c = l >> 4;      // B col / D col = oc; k-chunk = c
    int y  = r0 + w;

    v4h bf[9];
    int cb2 = c * 32 + oc * 2;
    #pragma unroll
    for (int s = 0; s < 9; ++s)
        bf[s] = *reinterpret_cast<const v4h*>(&wB[s * 128 + cb2]);

    float bias = bl[oc] + (isref ? el[oc] : 0.f);
    v4f binit; binit[0] = bias; binit[1] = bias; binit[2] = bias; binit[3] = bias;

    bf16* op = (isref ? R : A) + (size_t)img * IMGSZ;

    #pragma unroll
    for (int xq = 0; xq < 4; ++xq) {
        int ab = (w * 66 + xq * 16 + (l & 15)) * 12 + 2 * c;  // corner-biased
        v4f acc = binit;
        #pragma unroll
        for (int s = 0; s < 9; ++s) {
            v4h af = *reinterpret_cast<const v4h*>(&stg[ab + TAP_OFF(s)]);
            acc = __builtin_amdgcn_mfma_f32_16x16x16f16(af, bf[s], acc, 0, 0, 0);
        }
        #pragma unroll
        for (int g = 0; g < 4; ++g) {
            int x = xq * 16 + c * 4 + g;          // D row = c*4+g
            op[(((y << 6) + x) << 4) + oc] = __float2bfloat16(acc[g]);
        }
    }
}

// ---------------------------------------------------------------------------
// Attention stage. 256 threads, TPT=2 (two threads per token, 8 ch each).
// K/V transposed in LDS (kT[head][key], row stride S+12).
// v0.57: (a) q-projection compute+write under a single wave-uniform
// `if (i < HS)` -> s_cbranch_execz skips it entirely on the R-token waves
// (waves 2-3 in every stage); (b) s_setprio(1) around the phase-2 hot loop
// so waves in the exp/fdot2 section get issue priority over co-resident
// blocks' staging waves (8 independent blocks/CU at staggered phases).
// Output: bf16 in-place into A (X/Y); T writes only the f16x2 shadow A16.
// ---------------------------------------------------------------------------
template<int S, int SEQPB, int MINW, bool F16OUT>
__global__ __launch_bounds__(256, MINW) void attn_kernel(
    bf16* __restrict__ A, const bf16* __restrict__ R,
    unsigned* __restrict__ A16,
    int d2, int str1, int str2, int tokStride,
    const float* __restrict__ wq, const float* __restrict__ wk,
    const float* __restrict__ wv, const float* __restrict__ wo,
    const float* __restrict__ bo, const float* __restrict__ gw,
    const float* __restrict__ bw)
{
    constexpr int HS  = S / 2;             // queries per sequence
    constexpr int KQ  = S / 2;             // keys per phase-2 thread (halves)
    constexpr int TPT = 256 / (SEQPB * S); // must be 2
    static_assert(TPT == 2, "all stages use the pair-thread layout");
    constexpr int ITEMS = 256 / SEQPB;
    constexpr int NQG = ITEMS / 16;
    constexpr int QB  = HS / NQG;          // queries per phase-2 thread
    constexpr int QP  = QB / 2;
    constexpr int KROW = 10;               // q row stride (uints)
    constexpr int QROW = 20;               // o row stride (floats)
    constexpr int KTROW = S + 12;          // kT/vT row stride (uints)
    constexpr int LSQ = (SEQPB == 1) ? 0 : ((SEQPB == 2) ? 1 : 2);
    constexpr int NW3 = SEQPB * HS * 8 / 256;

    __shared__ float wolT[256];
    __shared__ unsigned wq2L[128], wk2L[128], wv2L[128];
    __shared__ float bol[16], gl[16], blw[16];
    __shared__ __align__(16) unsigned kvT[2 * SEQPB * 8 * KTROW]; // kT | vT; oL overlay
    __shared__ __align__(16) unsigned qL[SEQPB * HS * KROW];
    __shared__ int bases[SEQPB];
    unsigned* kT = kvT;
    unsigned* vT = kvT + SEQPB * 8 * KTROW;

    int t = threadIdx.x;
    wolT[(t & 15) * 16 + (t >> 4)] = wo[t];
    if (t < 128) {
        float2 qw = reinterpret_cast<const float2*>(wq)[t];
        float2 kw = reinterpret_cast<const float2*>(wk)[t];
        float2 vw = reinterpret_cast<const float2*>(wv)[t];
        wq2L[t] = pkh2(qw.x * QSCALE_LOG2E, qw.y * QSCALE_LOG2E);
        wk2L[t] = pkh2(kw.x, kw.y);
        wv2L[t] = pkh2(vw.x, vw.y);
    }
    if (t < 16) { bol[t] = bo[t]; gl[t] = gw[t]; blw[t] = bw[t]; }
    if (t < SEQPB) {
        int seq = blockIdx.x * SEQPB + t;
        bases[t] = (seq / d2) * str1 + (seq % d2) * str2;
    }
    __syncthreads();

    const float om[8] = {1.f, 0.31622776601683794f, 0.1f, 0.031622776601683794f,
                         0.01f, 0.0031622776601683794f, 0.001f, 0.00031622776601683794f};

    // ---- phase 1: token load, +posembed, LayerNorm, QKV (fdot2) -> LDS ----
    {
        int tokIdx = t >> 1;
        int half = t & 1;
        int db   = half * 8;
        int sq = tokIdx & (SEQPB - 1);
        int i  = tokIdx >> LSQ;
        const bf16* src = ((i < HS)
            ? (A + bases[sq] + (size_t)i * tokStride)
            : (R + bases[sq] + (size_t)(i - HS) * tokStride)) + db;
        uint4 u = *reinterpret_cast<const uint4*>(src);
        unsigned uu[4] = {u.x, u.y, u.z, u.w};
        float x[8];
        #pragma unroll
        for (int k = 0; k < 4; ++k) {
            union { unsigned u; float f; } lo, hi2;
            lo.u = uu[k] << 16; hi2.u = uu[k] & 0xffff0000u;
            x[2 * k] = lo.f; x[2 * k + 1] = hi2.f;
        }
        float fi = (float)i;
        #pragma unroll
        for (int k = 0; k < 8; ++k) {
            float sv, cv;
            __sincosf(fi * om[k], &sv, &cv);
            x[k] += half ? cv : sv;
        }
        float s8 = 0.f;
        #pragma unroll
        for (int k = 0; k < 8; ++k) s8 += x[k];
        float m = (s8 + __shfl_xor(s8, 1)) * (1.f / 16.f);
        float v8 = 0.f;
        #pragma unroll
        for (int k = 0; k < 8; ++k) { float d = x[k] - m; v8 = fmaf(d, d, v8); }
        float var = (v8 + __shfl_xor(v8, 1)) * (1.f / 16.f);
        float rs = rsqrtf(var + 1e-5f);

        unsigned xpm[4];
        #pragma unroll
        for (int e = 0; e < 4; ++e) {
            float a0 = (x[2 * e]     - m) * rs * gl[db + 2 * e]     + blw[db + 2 * e];
            float a1 = (x[2 * e + 1] - m) * rs * gl[db + 2 * e + 1] + blw[db + 2 * e + 1];
            xpm[e] = pkh2(a0, a1);
        }
        unsigned xp[8];
        #pragma unroll
        for (int e = 0; e < 4; ++e) {
            unsigned oth = __shfl_xor(xpm[e], 1);
            xp[e]     = half ? oth    : xpm[e];
            xp[e + 4] = half ? xpm[e] : oth;
        }
        // K/V projections for ALL tokens
        float kv[8], vv[8];
        #pragma unroll
        for (int dd = 0; dd < 8; ++dd) {
            int d = db + dd;
            float ak = 0.f, av = 0.f;
            #pragma unroll
            for (int c2 = 0; c2 < 8; ++c2) {
                ak = fdot2u(xp[c2], wk2L[d * 8 + c2], ak);
                av = fdot2u(xp[c2], wv2L[d * 8 + c2], av);
            }
            kv[dd] = ak; vv[dd] = av;
        }
        // transposed K/V: per head-row writes (4 heads per pair thread)
        int hb = db >> 1;   // first head
        #pragma unroll
        for (int e = 0; e < 4; ++e) {
            int hrow = (sq * 8 + hb + e) * KTROW + i;
            kT[hrow] = pkh2(kv[2 * e], kv[2 * e + 1]);
            vT[hrow] = packbf2(vv[2 * e], vv[2 * e + 1]);
        }
        // Q projection only for query tokens; i<HS is WAVE-uniform
        // (X/Y: i=t>>1, T: i=t>>3 -> boundary at t=128) => execz skip on
        // waves 2-3, saving the whole 64-fdot2 chain there.
        if (i < HS) {
            float qv[8];
            #pragma unroll
            for (int dd = 0; dd < 8; ++dd) {
                int d = db + dd;
                float aq = 0.f;
                #pragma unroll
                for (int c2 = 0; c2 < 8; ++c2)
                    aq = fdot2u(xp[c2], wq2L[d * 8 + c2], aq);
                qv[dd] = aq;
            }
            uint2* qr = reinterpret_cast<uint2*>(&qL[(sq * HS + i) * KROW + (db >> 1)]);
            #pragma unroll
            for (int e = 0; e < 2; ++e)
                qr[e] = make_uint2(pkh2(qv[4 * e], qv[4 * e + 1]),
                                   pkh2(qv[4 * e + 2], qv[4 * e + 3]));
        }
    }
    __syncthreads();

    // ---- phase 2: single-pass softmax (exp2 domain), contiguous key halves,
    //      b128 K/V loads (4 keys/instr), query-paired packed-FP32 accum ----
    int sq2 = t / ITEMS;
    int r   = t % ITEMS;
    int qg  = r >> 4;
    int hd  = (r >> 1) & 7;
    int half2 = r & 1;
    float* oL = reinterpret_cast<float*>(kvT);   // overlay after barrier
    {
        unsigned q2[QB];
        f32x2 l2[QP], a0p[QP], a1p[QP];
        #pragma unroll
        for (int qq = 0; qq < QB; ++qq)
            q2[qq] = qL[(sq2 * HS + qg * QB + qq) * KROW + hd];
        #pragma unroll
        for (int m = 0; m < QP; ++m) {
            l2[m] = f2(0.f, 0.f); a0p[m] = f2(0.f, 0.f); a1p[m] = f2(0.f, 0.f);
        }
        const unsigned* kp = &kT[(sq2 * 8 + hd) * KTROW + half2 * KQ];
        const unsigned* vp = &vT[(sq2 * 8 + hd) * KTROW + half2 * KQ];
        __builtin_amdgcn_s_setprio(1);   // favor hot-loop waves on this CU
        #pragma unroll 4
        for (int jb = 0; jb < KQ / 4; ++jb) {
            uint4 k4 = *reinterpret_cast<const uint4*>(kp + jb * 4);
            uint4 v4 = *reinterpret_cast<const uint4*>(vp + jb * 4);
            unsigned ks[4] = {k4.x, k4.y, k4.z, k4.w};
            unsigned vs[4] = {v4.x, v4.y, v4.z, v4.w};
            #pragma unroll
            for (int e = 0; e < 4; ++e) {
                union { unsigned u; float f; } v0, v1;
                v0.u = vs[e] << 16; v1.u = vs[e] & 0xffff0000u;
                f32x2 v00 = f2(v0.f, v0.f);
                f32x2 v11 = f2(v1.f, v1.f);
                #pragma unroll
                for (int m = 0; m < QP; ++m) {
                    f32x2 p2;
                    p2.x = __builtin_amdgcn_exp2f(fdot2u(q2[2 * m], ks[e], 0.f));
                    p2.y = __builtin_amdgcn_exp2f(fdot2u(q2[2 * m + 1], ks[e], 0.f));
                    l2[m] += p2;                                    // v_pk_add_f32
                    a0p[m] = __builtin_elementwise_fma(p2, v00, a0p[m]);
                    a1p[m] = __builtin_elementwise_fma(p2, v11, a1p[m]);
                }
            }
        }
        __builtin_amdgcn_s_setprio(0);
        #pragma unroll
        for (int m = 0; m < QP; ++m) {
            l2[m].x  += __shfl_xor(l2[m].x, 1);  l2[m].y  += __shfl_xor(l2[m].y, 1);
            a0p[m].x += __shfl_xor(a0p[m].x, 1); a0p[m].y += __shfl_xor(a0p[m].y, 1);
            a1p[m].x += __shfl_xor(a1p[m].x, 1); a1p[m].y += __shfl_xor(a1p[m].y, 1);
        }
        __syncthreads();   // all kT/vT/qL reads done; kvT reusable as oL
        if (half2 == 0) {
            #pragma unroll
            for (int m = 0; m < QP; ++m) {
                float inv0 = 1.f / l2[m].x;
                float inv1 = 1.f / l2[m].y;
                *reinterpret_cast<float2*>(
                    &oL[(sq2 * HS + qg * QB + 2 * m) * QROW + 2 * hd]) =
                    make_float2(a0p[m].x * inv0, a1p[m].x * inv0);
                *reinterpret_cast<float2*>(
                    &oL[(sq2 * HS + qg * QB + 2 * m + 1) * QROW + 2 * hd]) =
                    make_float2(a0p[m].y * inv1, a1p[m].y * inv1);
            }
        }
    }
    __syncthreads();

    // ---- phase 3: out-proj; bf16 in-place (X/Y) or f16 shadow only (T) ----
    #pragma unroll
    for (int rep = 0; rep < NW3; ++rep) {
        int idx = t + rep * 256;
        int cp  = idx & 7;
        int g   = idx >> 3;
        int sq3 = g & (SEQPB - 1);
        int tok = g >> LSQ;
        const float* orow = &oL[(sq3 * HS + tok) * QROW];
        float acc0 = bol[2 * cp], acc1 = bol[2 * cp + 1];
        #pragma unroll
        for (int d = 0; d < 16; ++d) {
            acc0 = fmaf(orow[d], wolT[d * 16 + 2 * cp], acc0);
            acc1 = fmaf(orow[d], wolT[d * 16 + 2 * cp + 1], acc1);
        }
        int off = bases[sq3] + tok * tokStride;
        if constexpr (F16OUT)
            A16[(off >> 1) + cp] = pkh2(acc0, acc1);   // conv_out consumes f16
        else
            *reinterpret_cast<unsigned*>(A + off + 2 * cp) = packbf2(acc0, acc1);
    }
}

// ---------------------------------------------------------------------------
// Kernel 5 (MFMA): out = hidden + conv(rest).  Input = A16 f16x2 shadow.
// ---------------------------------------------------------------------------
__global__ __launch_bounds__(256) void conv_out_kernel(
    const unsigned* __restrict__ A16, const float* __restrict__ hid,
    const float* __restrict__ pw, const float* __restrict__ pb,
    float* __restrict__ out)
{
    __shared__ __align__(16) unsigned stg[4 * 66 * 12];   // 12672 B
    __shared__ __align__(16) unsigned wB[1152];
    __shared__ float bl[16];

    int t = threadIdx.x;
    int bid = blockIdx.x;          // 1024 blocks = 32 img x 32 row-pairs
    int rg  = bid & 31;
    int img = bid >> 5;
    int r0  = rg << 1;

    stage_wB(pw, wB, t);
    if (t < 16) bl[t] = pb[t];

    const unsigned* inp = A16 + ((size_t)img << 15);   // 8 uints / pixel
    for (int s2 = t; s2 < 264; s2 += 256) {            // 4 rows x 66
        int rr = s2 / 66, xi = s2 - rr * 66;
        int y = r0 - 1 + rr, px = xi - 1;
        uint4* dst = reinterpret_cast<uint4*>(&stg[(rr * 66 + xi) * 12]);
        if ((unsigned)y < 64u && (unsigned)px < 64u) {
            const uint4* sp = reinterpret_cast<const uint4*>(
                inp + (((y << 6) + px) << 3));
            dst[0] = sp[0];
            dst[1] = sp[1];
        } else {
            dst[0] = make_uint4(0, 0, 0, 0);
            dst[1] = make_uint4(0, 0, 0, 0);
        }
    }
    __syncthreads();

    int l  = t & 63, w = t >> 6;
    int oc = l & 15, c = l >> 4;

    v4h bf[9];
    int cb2 = c * 32 + oc * 2;
    #pragma unroll
    for (int s = 0; s < 9; ++s)
        bf[s] = *reinterpret_cast<const v4h*>(&wB[s * 128 + cb2]);

    float bias = bl[oc];
    v4f binit; binit[0] = bias; binit[1] = bias; binit[2] = bias; binit[3] = bias;
    size_t obase = (size_t)img * IMGSZ;

    #pragma unroll
    for (int tq = 0; tq < 2; ++tq) {
        int tile = w * 2 + tq;
        int ro = tile >> 2, xq = tile & 3;
        int y  = r0 + ro;
        int ab = (ro * 66 + xq * 16 + (l & 15)) * 12 + 2 * c;
        v4f acc = binit;
        #pragma unroll
        for (int s = 0; s < 9; ++s) {
            v4h af = *reinterpret_cast<const v4h*>(&stg[ab + TAP_OFF(s)]);
            acc = __builtin_amdgcn_mfma_f32_16x16x16f16(af, bf[s], acc, 0, 0, 0);
        }
        #pragma unroll
        for (int g = 0; g < 4; ++g) {
            int x = xq * 16 + c * 4 + g;
            size_t o = obase + (size_t)(((y << 6) + x) << 4) + oc;
            out[o] = acc[g] + hid[o];
        }
    }
}

// ---------------------------------------------------------------------------
extern "C" void kernel_launch(void* const* d_in, const int* in_sizes, int n_in,
                              void* d_out, int out_size, void* d_ws, size_t ws_size,
                              hipStream_t stream) {
    const float* hid  = (const float*)d_in[0];
    const float* ref  = (const float*)d_in[1];
    const float* emb  = (const float*)d_in[2];
    const float* ciw  = (const float*)d_in[3];
    const float* cib  = (const float*)d_in[4];
    const float* e1w  = (const float*)d_in[5];
    const float* e1b  = (const float*)d_in[6];
    const float* e2w  = (const float*)d_in[7];
    const float* e2b  = (const float*)d_in[8];
    const float* wqx  = (const float*)d_in[9];
    const float* wkx  = (const float*)d_in[10];
    const float* wvx  = (const float*)d_in[11];
    const float* wox  = (const float*)d_in[12];
    const float* box_ = (const float*)d_in[13];
    const float* wqy  = (const float*)d_in[14];
    const float* wky  = (const float*)d_in[15];
    const float* wvy  = (const float*)d_in[16];
    const float* woy  = (const float*)d_in[17];
    const float* boy  = (const float*)d_in[18];
    const float* wqt  = (const float*)d_in[19];
    const float* wkt  = (const float*)d_in[20];
    const float* wvt  = (const float*)d_in[21];
    const float* wot  = (const float*)d_in[22];
    const float* bot  = (const float*)d_in[23];
    const float* ng   = (const float*)d_in[24];
    const float* nb   = (const float*)d_in[25];
    const float* pjw  = (const float*)d_in[26];
    const float* pjb  = (const float*)d_in[27];

    bf16* A = (bf16*)d_ws;     // 4 MiB in workspace
    unsigned* A16 = (unsigned*)((char*)d_ws + (4 << 20));  // 4 MiB f16 shadow
    bf16* R = (bf16*)d_out;    // 4 MiB scratch inside the 8 MiB f32 output buf
                               // (fully overwritten by conv_out at the end)

    // MFMA conv stem: 1024 blocks x 4 rows (both halves)
    conv_in_kernel<<<2 * NIMG * (HH / 4), 256, 0, stream>>>(
        hid, ref, ciw, cib, emb, e1w, e1b, e2w, e2b, A, R);

    // Stage X: seq=(b,f,h), S=2W=128, token stride 16, TPT=2
    attn_kernel<128, 1, 4, false><<<BB * FF * HH, 256, 0, stream>>>(
        A, R, nullptr, 1, WW * CC, 0, CC, wqx, wkx, wvx, wox, box_, ng, nb);
    // Stage Y: seq=(b,f,w), S=2H=128, tok stride W*C
    attn_kernel<128, 1, 4, false><<<BB * FF * WW, 256, 0, stream>>>(
        A, R, nullptr, WW, IMGSZ, CC, WW * CC, wqy, wky, wvy, woy, boy, ng, nb);
    // Stage T: seq=(b,h,w), S=2F=32; writes f16 shadow A16 only
    attn_kernel<32, 4, 4, true><<<(BB * HH * WW) / 4, 256, 0, stream>>>(
        A, R, A16, HH * WW, FF * IMGSZ, CC, IMGSZ, wqt, wkt, wvt, wot, bot, ng, nb);

    // MFMA conv_out: 1024 blocks x 2 rows
    conv_out_kernel<<<NIMG * (HH / 2), 256, 0, stream>>>(
        A16, hid, pjw, pjb, (float*)d_out);
}

// Round 13
// 221.718 us; speedup vs baseline: 1.0582x; 1.0582x over previous
//
#include <hip/hip_runtime.h>
#include <hip/hip_bf16.h>

typedef __hip_bfloat16 bf16;
// match the builtin's own return type (__fp16 ext_vector(2)) exactly
using hf2 = decltype(__builtin_amdgcn_cvt_pkrtz(0.f, 0.f));
typedef float f32x2 __attribute__((ext_vector_type(2)));
typedef _Float16 v4h __attribute__((ext_vector_type(4)));   // MFMA A/B frag
typedef float v4f __attribute__((ext_vector_type(4)));      // MFMA C/D frag

// ---------------------------------------------------------------------------
// Problem constants
// ---------------------------------------------------------------------------
#define BB   2
#define FF   16
#define HH   64
#define WW   64
#define CC   16     // in/out channels == MID
#define NIMG (BB*FF)        // 32
#define PIX  (HH*WW)        // 4096
#define IMGSZ (PIX*CC)      // 65536 elements per image (channel-last)

// scale(=1/sqrt(2)) * log2(e): folded into staged Wq; softmax uses raw v_exp_f32
#define QSCALE_LOG2E 1.0201394f

// ---- packed f16x2 helpers (v_cvt_pkrtz_f16_f32 / v_dot2_f32_f16) ----
__device__ __forceinline__ unsigned pkh2(float a, float b) {
    union { hf2 h; unsigned u; } x;
    x.h = __builtin_amdgcn_cvt_pkrtz(a, b);
    return x.u;
}
__device__ __forceinline__ float fdot2u(unsigned a, unsigned b, float c) {
    union { unsigned u; hf2 h; } A, B;
    A.u = a; B.u = b;
    return __builtin_amdgcn_fdot2(A.h, B.h, c, false);
}
__device__ __forceinline__ f32x2 f2(float a, float b) {
    f32x2 r; r.x = a; r.y = b; return r;
}

// ---- 16-element fp32 I/O ----
__device__ __forceinline__ void ld16f(const float* p, float* x) {
    const float4* p4 = reinterpret_cast<const float4*>(p);
    #pragma unroll
    for (int q = 0; q < 4; ++q) {
        float4 v = p4[q];
        x[4 * q] = v.x; x[4 * q + 1] = v.y; x[4 * q + 2] = v.z; x[4 * q + 3] = v.w;
    }
}

__device__ __forceinline__ unsigned packbf2(float a, float b) {
    union { bf16 h[2]; unsigned u; } pk;
    pk.h[0] = __float2bfloat16(a);
    pk.h[1] = __float2bfloat16(b);
    return pk.u;
}

// Conv weight prepack into MFMA-B layout: wB[(tap*4+chunk)*16+oc] = 4 f16 of
// w[oc][ic=chunk*4..+3][tap].  576 8-byte entries (4.6 KB).
__device__ __forceinline__ void stage_wB(const float* __restrict__ w,
                                         unsigned* __restrict__ wB, int t) {
    for (int e = t; e < 576; e += 256) {
        int oc = e & 15;
        int c  = (e >> 4) & 3;
        int s  = e >> 6;                 // tap 0..8
        const float* wp = w + (oc * 16 + c * 4) * 9 + s;   // ic stride = 9
        wB[e * 2]     = pkh2(wp[0],  wp[9]);
        wB[e * 2 + 1] = pkh2(wp[18], wp[27]);
    }
}

// per-tap LDS (uint) offset inside the halo-staged tile:
// taps s=0..8 -> (dy,dx) = (s/3-1, s%3-1); corner-biased base => offset
// ((s/3)*66 + s%3) * 12 uints (compile-time per unrolled step).
#define TAP_OFF(s) ((((s) / 3) * 66 + ((s) % 3)) * 12)

// ---------------------------------------------------------------------------
// Kernel 1 (MFMA): conv stem on hidden (->A) and ref (->R, + fused emb-MLP).
// ---------------------------------------------------------------------------
__global__ __launch_bounds__(256) void conv_in_kernel(
    const float* __restrict__ hid, const float* __restrict__ ref,
    const float* __restrict__ cw, const float* __restrict__ cb,
    const float* __restrict__ emb,
    const float* __restrict__ e1w, const float* __restrict__ e1b,
    const float* __restrict__ e2w, const float* __restrict__ e2b,
    bf16* __restrict__ A, bf16* __restrict__ R)
{
    __shared__ __align__(16) unsigned stg[6 * 66 * 12];   // 19008 B
    __shared__ __align__(16) unsigned wB[1152];           // 4608 B
    __shared__ float bl[16], hl[16], el[16];

    int t = threadIdx.x;
    int bid = blockIdx.x;          // 1024 blocks
    int rg   = bid & 15;
    int img2 = bid >> 4;           // 0..63, block-uniform
    int isref = img2 >> 5;
    int img   = img2 & 31;
    int bi    = img >> 4;
    int r0    = rg << 2;

    stage_wB(cw, wB, t);
    if (t < 16) bl[t] = cb[t];

    if (isref) {   // block-uniform branch: internal barriers safe
        float* red = reinterpret_cast<float*>(stg);   // overlay, freed below
        {
            int o = t >> 4, seg = t & 15;
            const float* er = emb + bi * 512 + seg * 32;
            const float* wr = e1w + o * 512 + seg * 32;
            float p = 0.f;
            #pragma unroll
            for (int k = 0; k < 32; ++k) p = fmaf(er[k], wr[k], p);
            red[t] = p;
        }
        __syncthreads();
        if (t < 16) {
            float acc = e1b[t];
            #pragma unroll
            for (int s = 0; s < 16; ++s) acc += red[t * 16 + s];
            hl[t] = acc / (1.f + __expf(-acc));   // silu
        }
        __syncthreads();
        if (t < 16) {
            float acc = e2b[t];
            #pragma unroll
            for (int k = 0; k < 16; ++k) acc = fmaf(hl[k], e2w[t * 16 + k], acc);
            el[t] = acc;
        }
        __syncthreads();   // red region free
    }

    // ---- stage 6 halo rows (r0-1..r0+4) x 66 cols, f16x2-packed ----
    const float* inp = (isref ? ref : hid) + (size_t)img * IMGSZ;
    for (int s2 = t; s2 < 396; s2 += 256) {
        int rr = s2 / 66, xi = s2 - rr * 66;
        int y = r0 - 1 + rr, px = xi - 1;
        uint4* dst = reinterpret_cast<uint4*>(&stg[(rr * 66 + xi) * 12]);
        if ((unsigned)y < 64u && (unsigned)px < 64u) {
            float xv[16];
            ld16f(inp + (((y << 6) + px) << 4), xv);
            dst[0] = make_uint4(pkh2(xv[0], xv[1]),  pkh2(xv[2], xv[3]),
                                pkh2(xv[4], xv[5]),  pkh2(xv[6], xv[7]));
            dst[1] = make_uint4(pkh2(xv[8], xv[9]),  pkh2(xv[10], xv[11]),
                                pkh2(xv[12], xv[13]), pkh2(xv[14], xv[15]));
        } else {
            dst[0] = make_uint4(0, 0, 0, 0);
            dst[1] = make_uint4(0, 0, 0, 0);
        }
    }
    __syncthreads();

    // ---- implicit-GEMM conv via MFMA ----
    int l  = t & 63, w = t >> 6;
    int oc = l & 15, c = l >> 4;      // B col / D col = oc; k-chunk = c
    int y  = r0 + w;

    v4h bf[9];
    int cb2 = c * 32 + oc * 2;
    #pragma unroll
    for (int s = 0; s < 9; ++s)
        bf[s] = *reinterpret_cast<const v4h*>(&wB[s * 128 + cb2]);

    float bias = bl[oc] + (isref ? el[oc] : 0.f);
    v4f binit; binit[0] = bias; binit[1] = bias; binit[2] = bias; binit[3] = bias;

    bf16* op = (isref ? R : A) + (size_t)img * IMGSZ;

    #pragma unroll
    for (int xq = 0; xq < 4; ++xq) {
        int ab = (w * 66 + xq * 16 + (l & 15)) * 12 + 2 * c;  // corner-biased
        v4f acc = binit;
        #pragma unroll
        for (int s = 0; s < 9; ++s) {
            v4h af = *reinterpret_cast<const v4h*>(&stg[ab + TAP_OFF(s)]);
            acc = __builtin_amdgcn_mfma_f32_16x16x16f16(af, bf[s], acc, 0, 0, 0);
        }
        #pragma unroll
        for (int g = 0; g < 4; ++g) {
            int x = xq * 16 + c * 4 + g;          // D row = c*4+g
            op[(((y << 6) + x) << 4) + oc] = __float2bfloat16(acc[g]);
        }
    }
}

// ---------------------------------------------------------------------------
// Attention stage. 256 threads, TPT=2 (two threads per token, 8 ch each).
// K/V transposed in LDS (kT[head][key], row stride S+12).  MINW=4.
// Output: bf16 in-place into A (X/Y); T writes only the f16x2 shadow A16.
// ---------------------------------------------------------------------------
template<int S, int SEQPB, int MINW, bool F16OUT>
__global__ __launch_bounds__(256, MINW) void attn_kernel(
    bf16* __restrict__ A, const bf16* __restrict__ R,
    unsigned* __restrict__ A16,
    int d2, int str1, int str2, int tokStride,
    const float* __restrict__ wq, const float* __restrict__ wk,
    const float* __restrict__ wv, const float* __restrict__ wo,
    const float* __restrict__ bo, const float* __restrict__ gw,
    const float* __restrict__ bw)
{
    constexpr int HS  = S / 2;             // queries per sequence
    constexpr int KQ  = S / 2;             // keys per phase-2 thread (halves)
    constexpr int TPT = 256 / (SEQPB * S); // must be 2
    static_assert(TPT == 2, "all stages use the pair-thread layout");
    constexpr int ITEMS = 256 / SEQPB;
    constexpr int NQG = ITEMS / 16;
    constexpr int QB  = HS / NQG;          // queries per phase-2 thread
    constexpr int QP  = QB / 2;
    constexpr int KROW = 10;               // q row stride (uints)
    constexpr int QROW = 20;               // o row stride (floats)
    constexpr int KTROW = S + 12;          // kT/vT row stride (uints)
    constexpr int LSQ = (SEQPB == 1) ? 0 : ((SEQPB == 2) ? 1 : 2);
    constexpr int NW3 = SEQPB * HS * 8 / 256;

    __shared__ float wolT[256];
    __shared__ unsigned wq2L[128], wk2L[128], wv2L[128];
    __shared__ float bol[16], gl[16], blw[16];
    __shared__ __align__(16) unsigned kvT[2 * SEQPB * 8 * KTROW]; // kT | vT; oL overlay
    __shared__ __align__(16) unsigned qL[SEQPB * HS * KROW];
    __shared__ int bases[SEQPB];
    unsigned* kT = kvT;
    unsigned* vT = kvT + SEQPB * 8 * KTROW;

    int t = threadIdx.x;
    wolT[(t & 15) * 16 + (t >> 4)] = wo[t];
    if (t < 128) {
        float2 qw = reinterpret_cast<const float2*>(wq)[t];
        float2 kw = reinterpret_cast<const float2*>(wk)[t];
        float2 vw = reinterpret_cast<const float2*>(wv)[t];
        wq2L[t] = pkh2(qw.x * QSCALE_LOG2E, qw.y * QSCALE_LOG2E);
        wk2L[t] = pkh2(kw.x, kw.y);
        wv2L[t] = pkh2(vw.x, vw.y);
    }
    if (t < 16) { bol[t] = bo[t]; gl[t] = gw[t]; blw[t] = bw[t]; }
    if (t < SEQPB) {
        int seq = blockIdx.x * SEQPB + t;
        bases[t] = (seq / d2) * str1 + (seq % d2) * str2;
    }
    __syncthreads();

    const float om[8] = {1.f, 0.31622776601683794f, 0.1f, 0.031622776601683794f,
                         0.01f, 0.0031622776601683794f, 0.001f, 0.00031622776601683794f};

    // ---- phase 1: token load, +posembed, LayerNorm, QKV (fdot2) -> LDS ----
    {
        int tokIdx = t >> 1;
        int half = t & 1;
        int db   = half * 8;
        int sq = tokIdx & (SEQPB - 1);
        int i  = tokIdx >> LSQ;
        const bf16* src = ((i < HS)
            ? (A + bases[sq] + (size_t)i * tokStride)
            : (R + bases[sq] + (size_t)(i - HS) * tokStride)) + db;
        uint4 u = *reinterpret_cast<const uint4*>(src);
        unsigned uu[4] = {u.x, u.y, u.z, u.w};
        float x[8];
        #pragma unroll
        for (int k = 0; k < 4; ++k) {
            union { unsigned u; float f; } lo, hi2;
            lo.u = uu[k] << 16; hi2.u = uu[k] & 0xffff0000u;
            x[2 * k] = lo.f; x[2 * k + 1] = hi2.f;
        }
        float fi = (float)i;
        #pragma unroll
        for (int k = 0; k < 8; ++k) {
            float sv, cv;
            __sincosf(fi * om[k], &sv, &cv);
            x[k] += half ? cv : sv;
        }
        float s8 = 0.f;
        #pragma unroll
        for (int k = 0; k < 8; ++k) s8 += x[k];
        float m = (s8 + __shfl_xor(s8, 1)) * (1.f / 16.f);
        float v8 = 0.f;
        #pragma unroll
        for (int k = 0; k < 8; ++k) { float d = x[k] - m; v8 = fmaf(d, d, v8); }
        float var = (v8 + __shfl_xor(v8, 1)) * (1.f / 16.f);
        float rs = rsqrtf(var + 1e-5f);

        unsigned xpm[4];
        #pragma unroll
        for (int e = 0; e < 4; ++e) {
            float a0 = (x[2 * e]     - m) * rs * gl[db + 2 * e]     + blw[db + 2 * e];
            float a1 = (x[2 * e + 1] - m) * rs * gl[db + 2 * e + 1] + blw[db + 2 * e + 1];
            xpm[e] = pkh2(a0, a1);
        }
        unsigned xp[8];
        #pragma unroll
        for (int e = 0; e < 4; ++e) {
            unsigned oth = __shfl_xor(xpm[e], 1);
            xp[e]     = half ? oth    : xpm[e];
            xp[e + 4] = half ? xpm[e] : oth;
        }
        float qv[8], kv[8], vv[8];
        #pragma unroll
        for (int dd = 0; dd < 8; ++dd) {
            int d = db + dd;
            float aq = 0.f, ak = 0.f, av = 0.f;
            #pragma unroll
            for (int c2 = 0; c2 < 8; ++c2) {
                aq = fdot2u(xp[c2], wq2L[d * 8 + c2], aq);
                ak = fdot2u(xp[c2], wk2L[d * 8 + c2], ak);
                av = fdot2u(xp[c2], wv2L[d * 8 + c2], av);
            }
            qv[dd] = aq; kv[dd] = ak; vv[dd] = av;
        }
        // transposed K/V: per head-row writes (4 heads per pair thread)
        int hb = db >> 1;   // first head
        #pragma unroll
        for (int e = 0; e < 4; ++e) {
            int hrow = (sq * 8 + hb + e) * KTROW + i;
            kT[hrow] = pkh2(kv[2 * e], kv[2 * e + 1]);
            vT[hrow] = packbf2(vv[2 * e], vv[2 * e + 1]);
        }
        if (i < HS) {
            uint2* qr = reinterpret_cast<uint2*>(&qL[(sq * HS + i) * KROW + (db >> 1)]);
            #pragma unroll
            for (int e = 0; e < 2; ++e)
                qr[e] = make_uint2(pkh2(qv[4 * e], qv[4 * e + 1]),
                                   pkh2(qv[4 * e + 2], qv[4 * e + 3]));
        }
    }
    __syncthreads();

    // ---- phase 2: single-pass softmax (exp2 domain), contiguous key halves,
    //      b128 K/V loads (4 keys/instr), query-paired packed-FP32 accum ----
    int sq2 = t / ITEMS;
    int r   = t % ITEMS;
    int qg  = r >> 4;
    int hd  = (r >> 1) & 7;
    int half2 = r & 1;
    float* oL = reinterpret_cast<float*>(kvT);   // overlay after barrier
    {
        unsigned q2[QB];
        f32x2 l2[QP], a0p[QP], a1p[QP];
        #pragma unroll
        for (int qq = 0; qq < QB; ++qq)
            q2[qq] = qL[(sq2 * HS + qg * QB + qq) * KROW + hd];
        #pragma unroll
        for (int m = 0; m < QP; ++m) {
            l2[m] = f2(0.f, 0.f); a0p[m] = f2(0.f, 0.f); a1p[m] = f2(0.f, 0.f);
        }
        const unsigned* kp = &kT[(sq2 * 8 + hd) * KTROW + half2 * KQ];
        const unsigned* vp = &vT[(sq2 * 8 + hd) * KTROW + half2 * KQ];
        #pragma unroll 4
        for (int jb = 0; jb < KQ / 4; ++jb) {
            uint4 k4 = *reinterpret_cast<const uint4*>(kp + jb * 4);
            uint4 v4 = *reinterpret_cast<const uint4*>(vp + jb * 4);
            unsigned ks[4] = {k4.x, k4.y, k4.z, k4.w};
            unsigned vs[4] = {v4.x, v4.y, v4.z, v4.w};
            #pragma unroll
            for (int e = 0; e < 4; ++e) {
                union { unsigned u; float f; } v0, v1;
                v0.u = vs[e] << 16; v1.u = vs[e] & 0xffff0000u;
                f32x2 v00 = f2(v0.f, v0.f);
                f32x2 v11 = f2(v1.f, v1.f);
                #pragma unroll
                for (int m = 0; m < QP; ++m) {
                    f32x2 p2;
                    p2.x = __builtin_amdgcn_exp2f(fdot2u(q2[2 * m], ks[e], 0.f));
                    p2.y = __builtin_amdgcn_exp2f(fdot2u(q2[2 * m + 1], ks[e], 0.f));
                    l2[m] += p2;                                    // v_pk_add_f32
                    a0p[m] = __builtin_elementwise_fma(p2, v00, a0p[m]);
                    a1p[m] = __builtin_elementwise_fma(p2, v11, a1p[m]);
                }
            }
        }
        #pragma unroll
        for (int m = 0; m < QP; ++m) {
            l2[m].x  += __shfl_xor(l2[m].x, 1);  l2[m].y  += __shfl_xor(l2[m].y, 1);
            a0p[m].x += __shfl_xor(a0p[m].x, 1); a0p[m].y += __shfl_xor(a0p[m].y, 1);
            a1p[m].x += __shfl_xor(a1p[m].x, 1); a1p[m].y += __shfl_xor(a1p[m].y, 1);
        }
        __syncthreads();   // all kT/vT/qL reads done; kvT reusable as oL
        if (half2 == 0) {
            #pragma unroll
            for (int m = 0; m < QP; ++m) {
                float inv0 = 1.f / l2[m].x;
                float inv1 = 1.f / l2[m].y;
                *reinterpret_cast<float2*>(
                    &oL[(sq2 * HS + qg * QB + 2 * m) * QROW + 2 * hd]) =
                    make_float2(a0p[m].x * inv0, a1p[m].x * inv0);
                *reinterpret_cast<float2*>(
                    &oL[(sq2 * HS + qg * QB + 2 * m + 1) * QROW + 2 * hd]) =
                    make_float2(a0p[m].y * inv1, a1p[m].y * inv1);
            }
        }
    }
    __syncthreads();

    // ---- phase 3: out-proj; bf16 in-place (X/Y) or f16 shadow only (T) ----
    #pragma unroll
    for (int rep = 0; rep < NW3; ++rep) {
        int idx = t + rep * 256;
        int cp  = idx & 7;
        int g   = idx >> 3;
        int sq3 = g & (SEQPB - 1);
        int tok = g >> LSQ;
        const float* orow = &oL[(sq3 * HS + tok) * QROW];
        float acc0 = bol[2 * cp], acc1 = bol[2 * cp + 1];
        #pragma unroll
        for (int d = 0; d < 16; ++d) {
            acc0 = fmaf(orow[d], wolT[d * 16 + 2 * cp], acc0);
            acc1 = fmaf(orow[d], wolT[d * 16 + 2 * cp + 1], acc1);
        }
        int off = bases[sq3] + tok * tokStride;
        if constexpr (F16OUT)
            A16[(off >> 1) + cp] = pkh2(acc0, acc1);   // conv_out consumes f16
        else
            *reinterpret_cast<unsigned*>(A + off + 2 * cp) = packbf2(acc0, acc1);
    }
}

// ---------------------------------------------------------------------------
// Kernel 5 (MFMA): out = hidden + conv(rest).  Input = A16 f16x2 shadow.
// ---------------------------------------------------------------------------
__global__ __launch_bounds__(256) void conv_out_kernel(
    const unsigned* __restrict__ A16, const float* __restrict__ hid,
    const float* __restrict__ pw, const float* __restrict__ pb,
    float* __restrict__ out)
{
    __shared__ __align__(16) unsigned stg[4 * 66 * 12];   // 12672 B
    __shared__ __align__(16) unsigned wB[1152];
    __shared__ float bl[16];

    int t = threadIdx.x;
    int bid = blockIdx.x;          // 1024 blocks = 32 img x 32 row-pairs
    int rg  = bid & 31;
    int img = bid >> 5;
    int r0  = rg << 1;

    stage_wB(pw, wB, t);
    if (t < 16) bl[t] = pb[t];

    const unsigned* inp = A16 + ((size_t)img << 15);   // 8 uints / pixel
    for (int s2 = t; s2 < 264; s2 += 256) {            // 4 rows x 66
        int rr = s2 / 66, xi = s2 - rr * 66;
        int y = r0 - 1 + rr, px = xi - 1;
        uint4* dst = reinterpret_cast<uint4*>(&stg[(rr * 66 + xi) * 12]);
        if ((unsigned)y < 64u && (unsigned)px < 64u) {
            const uint4* sp = reinterpret_cast<const uint4*>(
                inp + (((y << 6) + px) << 3));
            dst[0] = sp[0];
            dst[1] = sp[1];
        } else {
            dst[0] = make_uint4(0, 0, 0, 0);
            dst[1] = make_uint4(0, 0, 0, 0);
        }
    }
    __syncthreads();

    int l  = t & 63, w = t >> 6;
    int oc = l & 15, c = l >> 4;

    v4h bf[9];
    int cb2 = c * 32 + oc * 2;
    #pragma unroll
    for (int s = 0; s < 9; ++s)
        bf[s] = *reinterpret_cast<const v4h*>(&wB[s * 128 + cb2]);

    float bias = bl[oc];
    v4f binit; binit[0] = bias; binit[1] = bias; binit[2] = bias; binit[3] = bias;
    size_t obase = (size_t)img * IMGSZ;

    #pragma unroll
    for (int tq = 0; tq < 2; ++tq) {
        int tile = w * 2 + tq;
        int ro = tile >> 2, xq = tile & 3;
        int y  = r0 + ro;
        int ab = (ro * 66 + xq * 16 + (l & 15)) * 12 + 2 * c;
        v4f acc = binit;
        #pragma unroll
        for (int s = 0; s < 9; ++s) {
            v4h af = *reinterpret_cast<const v4h*>(&stg[ab + TAP_OFF(s)]);
            acc = __builtin_amdgcn_mfma_f32_16x16x16f16(af, bf[s], acc, 0, 0, 0);
        }
        #pragma unroll
        for (int g = 0; g < 4; ++g) {
            int x = xq * 16 + c * 4 + g;
            size_t o = obase + (size_t)(((y << 6) + x) << 4) + oc;
            out[o] = acc[g] + hid[o];
        }
    }
}

// ---------------------------------------------------------------------------
extern "C" void kernel_launch(void* const* d_in, const int* in_sizes, int n_in,
                              void* d_out, int out_size, void* d_ws, size_t ws_size,
                              hipStream_t stream) {
    const float* hid  = (const float*)d_in[0];
    const float* ref  = (const float*)d_in[1];
    const float* emb  = (const float*)d_in[2];
    const float* ciw  = (const float*)d_in[3];
    const float* cib  = (const float*)d_in[4];
    const float* e1w  = (const float*)d_in[5];
    const float* e1b  = (const float*)d_in[6];
    const float* e2w  = (const float*)d_in[7];
    const float* e2b  = (const float*)d_in[8];
    const float* wqx  = (const float*)d_in[9];
    const float* wkx  = (const float*)d_in[10];
    const float* wvx  = (const float*)d_in[11];
    const float* wox  = (const float*)d_in[12];
    const float* box_ = (const float*)d_in[13];
    const float* wqy  = (const float*)d_in[14];
    const float* wky  = (const float*)d_in[15];
    const float* wvy  = (const float*)d_in[16];
    const float* woy  = (const float*)d_in[17];
    const float* boy  = (const float*)d_in[18];
    const float* wqt  = (const float*)d_in[19];
    const float* wkt  = (const float*)d_in[20];
    const float* wvt  = (const float*)d_in[21];
    const float* wot  = (const float*)d_in[22];
    const float* bot  = (const float*)d_in[23];
    const float* ng   = (const float*)d_in[24];
    const float* nb   = (const float*)d_in[25];
    const float* pjw  = (const float*)d_in[26];
    const float* pjb  = (const float*)d_in[27];

    bf16* A = (bf16*)d_ws;     // 4 MiB in workspace
    unsigned* A16 = (unsigned*)((char*)d_ws + (4 << 20));  // 4 MiB f16 shadow
    bf16* R = (bf16*)d_out;    // 4 MiB scratch inside the 8 MiB f32 output buf
                               // (fully overwritten by conv_out at the end)

    // MFMA conv stem: 1024 blocks x 4 rows (both halves)
    conv_in_kernel<<<2 * NIMG * (HH / 4), 256, 0, stream>>>(
        hid, ref, ciw, cib, emb, e1w, e1b, e2w, e2b, A, R);

    // Stage X: seq=(b,f,h), S=2W=128, token stride 16, TPT=2
    attn_kernel<128, 1, 4, false><<<BB * FF * HH, 256, 0, stream>>>(
        A, R, nullptr, 1, WW * CC, 0, CC, wqx, wkx, wvx, wox, box_, ng, nb);
    // Stage Y: seq=(b,f,w), S=2H=128, tok stride W*C
    attn_kernel<128, 1, 4, false><<<BB * FF * WW, 256, 0, stream>>>(
        A, R, nullptr, WW, IMGSZ, CC, WW * CC, wqy, wky, wvy, woy, boy, ng, nb);
    // Stage T: seq=(b,h,w), S=2F=32; writes f16 shadow A16 only
    attn_kernel<32, 4, 4, true><<<(BB * HH * WW) / 4, 256, 0, stream>>>(
        A, R, A16, HH * WW, FF * IMGSZ, CC, IMGSZ, wqt, wkt, wvt, wot, bot, ng, nb);

    // MFMA conv_out: 1024 blocks x 2 rows
    conv_out_kernel<<<NIMG * (HH / 2), 256, 0, stream>>>(
        A16, hid, pjw, pjb, (float*)d_out);
}